// Round 8
// baseline (28.787 us; speedup 1.0000x reference)
//
#include <hip/hip_runtime.h>
#include <hip/hip_bf16.h>

#define CIN 32
#define HW 64
#define KK 64
#define PADDING 2
#define TH 4                    // tile rows
#define TCW 16                  // tile cols
#define WR 8                    // window rows = TH + 4
#define WC 20                   // window cols = TCW + 4
#define WPOS (CIN * WR * WC)    // 5120 positions; f32x2 each -> 40960 B LDS

typedef float f32x2 __attribute__((ext_vector_type(2)));

__device__ __constant__ float d_C[16][4] = {
    {0, 0, 0, 0},  {0, 0, 0, 1},  {0, 1, 0, -1}, {0, 1, 0, 0},
    {0, 0, 1, -1}, {0, 0, 1, 0},  {0, 1, 1, -2}, {0, 1, 1, -1},
    {1, -1, -1, 1},{1, -1, -1, 2},{1, 0, -1, 0}, {1, 0, -1, 1},
    {1, -1, 0, 0}, {1, -1, 0, 1}, {1, 0, 0, -1}, {1, 0, 0, 0}
};

__device__ __forceinline__ float rlf(unsigned v, int lane) {
    return __uint_as_float(__builtin_amdgcn_readlane(v, lane));
}
__device__ __forceinline__ f32x2 bc(float s) { return (f32x2){s, s}; }
__device__ __forceinline__ f32x2 gate2(float c0, float c1, float c2, float c3,
                                       f32x2 a, f32x2 b) {
    return __builtin_elementwise_fma(b,
               __builtin_elementwise_fma(a, bc(c3), bc(c2)),
               __builtin_elementwise_fma(a, bc(c1), bc(c0)));
}

// Single fused kernel. blockIdx = kh*512 + bp*64 + tile (tile = th*4 + tw).
// Phase 1: block computes its 32 k's coefs+offsets into LDS (temp area);
//          256 threads x 2 reps cover the 480 (k,node) coef tasks.
// Phase 2: each wave caches its 8 k's 608 dwords in 10 lane-strided VGPRs;
// Phase 3: LDS reused for the f32x2-interleaved 32x8x20 window;
// Phase 4: k-loop, uniforms extracted via compile-time readlane.
__global__ __launch_bounds__(256, 4) void logic_conv_fused(
    const float* __restrict__ x,
    const int* __restrict__ idx_h, const int* __restrict__ idx_w, const int* __restrict__ idx_c,
    const float* __restrict__ w0, const float* __restrict__ w1,
    const float* __restrict__ w2, const float* __restrict__ w3,
    float* __restrict__ out)
{
    __shared__ f32x2 xt[WPOS];
    float*    lds_f = (float*)xt;
    unsigned* lds_u = (unsigned*)xt;

    int tid = threadIdx.x;
    int kh  = blockIdx.x >> 9;
    int rem = blockIdx.x & 511;
    int bp  = rem >> 6;
    int t   = rem & 63;
    int r0  = (t >> 2) * TH;
    int c0  = (t & 3) * TCW;

    // ---- issue coef-input loads first (logits + indices); 2 tasks/thread ----
    float4 La[2][4];
    #pragma unroll
    for (int rep = 0; rep < 2; ++rep) {
        int t2 = tid + rep * 256;
        if (t2 < 480) {
            int kl = t2 / 15, nd = t2 - kl * 15;
            const float* wp; int nn;
            if (nd < 8)       { wp = w0; nn = nd; }
            else if (nd < 12) { wp = w1; nn = nd - 8; }
            else if (nd < 14) { wp = w2; nn = nd - 12; }
            else              { wp = w3; nn = 0; }
            const float4* lp = (const float4*)(wp + (size_t)(nn * KK + (kh * 32 + kl)) * 16);
            La[rep][0] = lp[0]; La[rep][1] = lp[1];
            La[rep][2] = lp[2]; La[rep][3] = lp[3];
        }
    }
    int kl_i = tid >> 3, nl = tid & 7;               // offset mapping (32k x 8 leaf-pairs)
    int oa = (kh * 32 + kl_i) * 8 + nl;
    int ob = 512 + oa;
    int ca = idx_c[oa], ha = idx_h[oa], wa = idx_w[oa];
    int cb = idx_c[ob], hb = idx_h[ob], wb = idx_w[ob];

    // ---- issue window loads (latency hides under coef math) ----
    const float* xb0 = x + (size_t)(2 * bp) * (CIN * HW * HW);
    const float* xb1 = xb0 + (CIN * HW * HW);
    f32x2 wv[20];
    #pragma unroll
    for (int i = 0; i < 20; ++i) {
        int e  = tid + i * 256;
        int c  = e / (WR * WC);
        int r  = e - c * (WR * WC);
        int rr = r / WC;
        int cc2 = r - rr * WC;
        int ih = r0 + rr - PADDING, iw = c0 + cc2 - PADDING;
        f32x2 v = {0.f, 0.f};
        if ((unsigned)ih < HW && (unsigned)iw < HW) {
            int go = (c * HW + ih) * HW + iw;
            v.x = xb0[go];
            v.y = xb1[go];
        }
        wv[i] = v;
    }

    // ---- coef softmax -> LDS temp area [32k][76 dwords] ----
    #pragma unroll
    for (int rep = 0; rep < 2; ++rep) {
        int t2 = tid + rep * 256;
        if (t2 < 480) {
            int kl = t2 / 15, nd = t2 - kl * 15;
            float l[16] = {La[rep][0].x, La[rep][0].y, La[rep][0].z, La[rep][0].w,
                           La[rep][1].x, La[rep][1].y, La[rep][1].z, La[rep][1].w,
                           La[rep][2].x, La[rep][2].y, La[rep][2].z, La[rep][2].w,
                           La[rep][3].x, La[rep][3].y, La[rep][3].z, La[rep][3].w};
            float m = l[0];
            #pragma unroll
            for (int g = 1; g < 16; ++g) m = fmaxf(m, l[g]);
            float p[16], s = 0.f;
            #pragma unroll
            for (int g = 0; g < 16; ++g) { p[g] = __expf(l[g] - m); s += p[g]; }
            float inv = 1.f / s;
            float c0v = 0, c1v = 0, c2v = 0, c3v = 0;
            #pragma unroll
            for (int g = 0; g < 16; ++g) {
                float w = p[g] * inv;
                c0v = fmaf(w, d_C[g][0], c0v);
                c1v = fmaf(w, d_C[g][1], c1v);
                c2v = fmaf(w, d_C[g][2], c2v);
                c3v = fmaf(w, d_C[g][3], c3v);
            }
            ((float4*)lds_f)[kl * 19 + nd] = (float4){c0v, c1v, c2v, c3v};
        }
    }
    // leaf byte-offsets in the f32x2 window
    lds_u[kl_i * 76 + 60 + nl] = (unsigned)((ca * (WR * WC) + ha * WC + wa) * 8);
    lds_u[kl_i * 76 + 68 + nl] = (unsigned)((cb * (WR * WC) + hb * WC + wb) * 8);
    __syncthreads();

    // ---- each wave caches its 8 k's 608 dwords, lane-strided ----
    int lane = tid & 63, wave = tid >> 6;
    unsigned cc[10];
    #pragma unroll
    for (int i = 0; i < 10; ++i)
        cc[i] = lds_u[wave * 608 + i * 64 + lane];
    __syncthreads();

    // ---- overwrite LDS with the interleaved window ----
    #pragma unroll
    for (int i = 0; i < 20; ++i)
        xt[tid + i * 256] = wv[i];
    __syncthreads();

    // ---- k-loop ----
    int tr = lane >> 4, tc = lane & 15;
    int pxb   = (tr * WC + tc) * 8;
    int pxout = (r0 + tr) * HW + (c0 + tc);
    float* outB0 = out + ((size_t)(2 * bp) << 18);
    float* outB1 = outB0 + (1 << 18);
    const char* xtb = (const char*)xt;
    int kbase = kh * 32 + wave * 8;

    #pragma unroll
    for (int j = 0; j < 8; ++j) {
        const int D = j * 76;
        f32x2 g[16];
        #pragma unroll
        for (int n = 0; n < 16; ++n) {
            int Dn = D + 60 + n;
            int off = (int)__builtin_amdgcn_readlane(cc[Dn >> 6], Dn & 63);
            g[n] = *(const f32x2*)(xtb + (off + pxb));
        }
        f32x2 v[8];
        #pragma unroll
        for (int n = 0; n < 8; ++n) {
            int Dc = D + 4 * n;
            v[n] = gate2(rlf(cc[Dc >> 6], Dc & 63), rlf(cc[(Dc + 1) >> 6], (Dc + 1) & 63),
                         rlf(cc[(Dc + 2) >> 6], (Dc + 2) & 63), rlf(cc[(Dc + 3) >> 6], (Dc + 3) & 63),
                         g[n], g[8 + n]);
        }
        f32x2 u[4];
        #pragma unroll
        for (int n = 0; n < 4; ++n) {
            int Dc = D + 32 + 4 * n;
            u[n] = gate2(rlf(cc[Dc >> 6], Dc & 63), rlf(cc[(Dc + 1) >> 6], (Dc + 1) & 63),
                         rlf(cc[(Dc + 2) >> 6], (Dc + 2) & 63), rlf(cc[(Dc + 3) >> 6], (Dc + 3) & 63),
                         v[2 * n], v[2 * n + 1]);
        }
        int Dc = D + 48;
        f32x2 t0 = gate2(rlf(cc[Dc >> 6], Dc & 63), rlf(cc[(Dc + 1) >> 6], (Dc + 1) & 63),
                         rlf(cc[(Dc + 2) >> 6], (Dc + 2) & 63), rlf(cc[(Dc + 3) >> 6], (Dc + 3) & 63),
                         u[0], u[1]);
        Dc = D + 52;
        f32x2 t1 = gate2(rlf(cc[Dc >> 6], Dc & 63), rlf(cc[(Dc + 1) >> 6], (Dc + 1) & 63),
                         rlf(cc[(Dc + 2) >> 6], (Dc + 2) & 63), rlf(cc[(Dc + 3) >> 6], (Dc + 3) & 63),
                         u[2], u[3]);
        Dc = D + 56;
        f32x2 r  = gate2(rlf(cc[Dc >> 6], Dc & 63), rlf(cc[(Dc + 1) >> 6], (Dc + 1) & 63),
                         rlf(cc[(Dc + 2) >> 6], (Dc + 2) & 63), rlf(cc[(Dc + 3) >> 6], (Dc + 3) & 63),
                         t0, t1);

        int ko = ((kbase + j) << 12) + pxout;
        outB0[ko] = r.x;
        outB1[ko] = r.y;
    }
}

extern "C" void kernel_launch(void* const* d_in, const int* in_sizes, int n_in,
                              void* d_out, int out_size, void* d_ws, size_t ws_size,
                              hipStream_t stream) {
    const float* x     = (const float*)d_in[0];
    const int*   idx_h = (const int*)d_in[1];
    const int*   idx_w = (const int*)d_in[2];
    const int*   idx_c = (const int*)d_in[3];
    const float* w0    = (const float*)d_in[4];
    const float* w1    = (const float*)d_in[5];
    const float* w2    = (const float*)d_in[6];
    const float* w3    = (const float*)d_in[7];
    float* out = (float*)d_out;

    // 2 k-halves * 8 batch-pairs * 64 tiles = 1024 blocks, single fused kernel
    hipLaunchKernelGGL(logic_conv_fused, dim3(1024), dim3(256), 0, stream,
                       x, idx_h, idx_w, idx_c, w0, w1, w2, w3, out);
}

// Round 9
// 21.752 us; speedup vs baseline: 1.3234x; 1.3234x over previous
//
#include <hip/hip_runtime.h>
#include <hip/hip_bf16.h>

#define CIN 32
#define HW 64
#define KK 64
#define NLEAF 8
#define PADDING 2
#define TH 4                    // tile rows
#define TCW 16                  // tile cols
#define WR 8                    // window rows = TH + 4
#define WC 20                   // window cols = TCW + 4
#define WPOS (CIN * WR * WC)    // 5120 positions; f32x2 each -> 40960 B LDS

typedef float f32x2 __attribute__((ext_vector_type(2)));

__device__ __constant__ float d_C[16][4] = {
    {0, 0, 0, 0},  {0, 0, 0, 1},  {0, 1, 0, -1}, {0, 1, 0, 0},
    {0, 0, 1, -1}, {0, 0, 1, 0},  {0, 1, 1, -2}, {0, 1, 1, -1},
    {1, -1, -1, 1},{1, -1, -1, 2},{1, 0, -1, 0}, {1, 0, -1, 1},
    {1, -1, 0, 0}, {1, -1, 0, 1}, {1, 0, 0, -1}, {1, 0, 0, 0}
};

// blocks 0..3: coefA[k*60 + node*4 + c]; block 4: loffA[k*16+n] = BYTE offset
// of leaf (c,dh,dw) in the f32x2-interleaved 32 x 8 x 20 window.
__global__ __launch_bounds__(256) void prep_kernel(
    const int* __restrict__ idx_h, const int* __restrict__ idx_w, const int* __restrict__ idx_c,
    const float* __restrict__ w0, const float* __restrict__ w1,
    const float* __restrict__ w2, const float* __restrict__ w3,
    float* __restrict__ coefA, int* __restrict__ loffA)
{
    if (blockIdx.x == 4) {
        int k = threadIdx.x;
        if (k < KK) {
            #pragma unroll
            for (int n = 0; n < 16; ++n) {
                int s = n >> 3, leaf = n & 7;
                int o = s * (KK * NLEAF) + k * NLEAF + leaf;
                loffA[k * 16 + n] = (idx_c[o] * (WR * WC) + idx_h[o] * WC + idx_w[o]) * 8;
            }
        }
        return;
    }
    int t = blockIdx.x * blockDim.x + threadIdx.x;
    if (t >= KK * 15) return;
    int k = t / 15, node = t % 15;
    const float* wp; int n;
    if (node < 8)       { wp = w0; n = node; }
    else if (node < 12) { wp = w1; n = node - 8; }
    else if (node < 14) { wp = w2; n = node - 12; }
    else                { wp = w3; n = 0; }
    const float* l = wp + (n * KK + k) * 16;
    float m = l[0];
    #pragma unroll
    for (int g = 1; g < 16; ++g) m = fmaxf(m, l[g]);
    float p[16], s = 0.f;
    #pragma unroll
    for (int g = 0; g < 16; ++g) { p[g] = expf(l[g] - m); s += p[g]; }
    float inv = 1.f / s;
    float c0 = 0, c1 = 0, c2 = 0, c3 = 0;
    #pragma unroll
    for (int g = 0; g < 16; ++g) {
        float w = p[g] * inv;
        c0 = fmaf(w, d_C[g][0], c0);
        c1 = fmaf(w, d_C[g][1], c1);
        c2 = fmaf(w, d_C[g][2], c2);
        c3 = fmaf(w, d_C[g][3], c3);
    }
    float* o = coefA + (k * 60 + node * 4);
    o[0] = c0; o[1] = c1; o[2] = c2; o[3] = c3;
}

__device__ __forceinline__ f32x2 bc(float s) { return (f32x2){s, s}; }
__device__ __forceinline__ f32x2 gate2(const float* c, f32x2 a, f32x2 b) {
    return __builtin_elementwise_fma(b,
               __builtin_elementwise_fma(a, bc(c[3]), bc(c[2])),
               __builtin_elementwise_fma(a, bc(c[1]), bc(c[0])));
}

// blockIdx = inner*8 + bp  (XCD-pinned: all 128 blocks of a batch-pair share
// one XCD's L2, which then holds that pair's 2.1 MB of x).
// inner = kh*64 + tile; tile = th*4 + tw. 4 waves x 8 k; lane = pixel of the
// 4x16 tile; f32x2 = 2 batch images.
__global__ __launch_bounds__(256) void logic_conv_kernel(
    const float* __restrict__ x, const int* __restrict__ loffA,
    const float* __restrict__ coefA, float* __restrict__ out)
{
    __shared__ f32x2 xt[WPOS];

    int tid   = threadIdx.x;
    int bp    = blockIdx.x & 7;          // batch-pair == XCD slot
    int inner = blockIdx.x >> 3;
    int kh    = inner >> 6;
    int t     = inner & 63;
    int r0  = (t >> 2) * TH;
    int c0  = (t & 3) * TCW;

    const float* xb0 = x + (size_t)(2 * bp) * (CIN * HW * HW);
    const float* xb1 = xb0 + (CIN * HW * HW);

    // Stage interleaved padded 32x8x20 windows for both images.
    #pragma unroll
    for (int i = 0; i < 20; ++i) {
        int e  = tid + i * 256;
        int c  = e / (WR * WC);
        int r  = e - c * (WR * WC);
        int rr = r / WC;
        int cc = r - rr * WC;
        int ih = r0 + rr - PADDING, iw = c0 + cc - PADDING;
        f32x2 v = {0.f, 0.f};
        if ((unsigned)ih < HW && (unsigned)iw < HW) {
            int go = (c * HW + ih) * HW + iw;
            v.x = xb0[go];
            v.y = xb1[go];
        }
        xt[e] = v;
    }
    __syncthreads();

    int lane = tid & 63, wave = tid >> 6;
    int tr = lane >> 4, tc = lane & 15;
    int pxb   = (tr * WC + tc) * 8;            // per-lane LDS byte offset
    int pxout = (r0 + tr) * HW + (c0 + tc);    // per-lane output element offset
    float* outB0 = out + ((size_t)(2 * bp) << 18);
    float* outB1 = outB0 + (1 << 18);
    const char* xtb = (const char*)xt;

    int k0 = __builtin_amdgcn_readfirstlane((kh << 5) + (wave << 3));

    #pragma unroll 2
    for (int i = 0; i < 8; ++i) {
        int k = k0 + i;
        const int*   L = loffA + (k << 4);
        const float* C = coefA + k * 60;

        f32x2 g[16];
        #pragma unroll
        for (int n = 0; n < 16; ++n)
            g[n] = *(const f32x2*)(xtb + (L[n] + pxb));

        f32x2 v[8];
        #pragma unroll
        for (int n = 0; n < 8; ++n)
            v[n] = gate2(C + 4 * n, g[n], g[8 + n]);
        f32x2 u[4];
        #pragma unroll
        for (int n = 0; n < 4; ++n)
            u[n] = gate2(C + 32 + 4 * n, v[2 * n], v[2 * n + 1]);
        f32x2 t0 = gate2(C + 48, u[0], u[1]);
        f32x2 t1 = gate2(C + 52, u[2], u[3]);
        f32x2 r  = gate2(C + 56, t0, t1);

        int ko = (k << 12) + pxout;
        __builtin_nontemporal_store(r.x, &outB0[ko]);
        __builtin_nontemporal_store(r.y, &outB1[ko]);
    }
}

extern "C" void kernel_launch(void* const* d_in, const int* in_sizes, int n_in,
                              void* d_out, int out_size, void* d_ws, size_t ws_size,
                              hipStream_t stream) {
    const float* x     = (const float*)d_in[0];
    const int*   idx_h = (const int*)d_in[1];
    const int*   idx_w = (const int*)d_in[2];
    const int*   idx_c = (const int*)d_in[3];
    const float* w0    = (const float*)d_in[4];
    const float* w1    = (const float*)d_in[5];
    const float* w2    = (const float*)d_in[6];
    const float* w3    = (const float*)d_in[7];
    float* out   = (float*)d_out;

    float* coefA = (float*)d_ws;                      // 15,360 B
    int*   loffA = (int*)((char*)d_ws + 16384);       // 4,096 B

    hipLaunchKernelGGL(prep_kernel, dim3(5), dim3(256), 0, stream,
                       idx_h, idx_w, idx_c, w0, w1, w2, w3, coefA, loffA);
    // 2 k-halves * 8 batch-pairs * 64 tiles = 1024 blocks, XCD-pinned by bp
    hipLaunchKernelGGL(logic_conv_kernel, dim3(1024), dim3(256), 0, stream,
                       x, loffA, coefA, out);
}

// Round 10
// 21.385 us; speedup vs baseline: 1.3462x; 1.0172x over previous
//
#include <hip/hip_runtime.h>
#include <hip/hip_bf16.h>

#define CIN 32
#define HW 64
#define KK 64
#define NLEAF 8
#define PADDING 2
#define TH 4                    // tile rows
#define TCW 16                  // tile cols
#define WR 8                    // window rows = TH + 4
#define WC 20                   // window cols = TCW + 4
#define WPOS (CIN * WR * WC)    // 5120 positions; f32x2 each -> 40960 B LDS

typedef float f32x2 __attribute__((ext_vector_type(2)));

__device__ __constant__ float d_C[16][4] = {
    {0, 0, 0, 0},  {0, 0, 0, 1},  {0, 1, 0, -1}, {0, 1, 0, 0},
    {0, 0, 1, -1}, {0, 0, 1, 0},  {0, 1, 1, -2}, {0, 1, 1, -1},
    {1, -1, -1, 1},{1, -1, -1, 2},{1, 0, -1, 0}, {1, 0, -1, 1},
    {1, -1, 0, 0}, {1, -1, 0, 1}, {1, 0, 0, -1}, {1, 0, 0, 0}
};

// blocks 0..3: coefA[k*60 + node*4 + c]; block 4: loffA[k*16+n] = BYTE offset
// of leaf (c,dh,dw) in the f32x2-interleaved 32 x 8 x 20 window.
__global__ __launch_bounds__(256) void prep_kernel(
    const int* __restrict__ idx_h, const int* __restrict__ idx_w, const int* __restrict__ idx_c,
    const float* __restrict__ w0, const float* __restrict__ w1,
    const float* __restrict__ w2, const float* __restrict__ w3,
    float* __restrict__ coefA, int* __restrict__ loffA)
{
    if (blockIdx.x == 4) {
        int k = threadIdx.x;
        if (k < KK) {
            #pragma unroll
            for (int n = 0; n < 16; ++n) {
                int s = n >> 3, leaf = n & 7;
                int o = s * (KK * NLEAF) + k * NLEAF + leaf;
                loffA[k * 16 + n] = (idx_c[o] * (WR * WC) + idx_h[o] * WC + idx_w[o]) * 8;
            }
        }
        return;
    }
    int t = blockIdx.x * blockDim.x + threadIdx.x;
    if (t >= KK * 15) return;
    int k = t / 15, node = t % 15;
    const float* wp; int n;
    if (node < 8)       { wp = w0; n = node; }
    else if (node < 12) { wp = w1; n = node - 8; }
    else if (node < 14) { wp = w2; n = node - 12; }
    else                { wp = w3; n = 0; }
    const float* l = wp + (n * KK + k) * 16;
    float m = l[0];
    #pragma unroll
    for (int g = 1; g < 16; ++g) m = fmaxf(m, l[g]);
    float p[16], s = 0.f;
    #pragma unroll
    for (int g = 0; g < 16; ++g) { p[g] = expf(l[g] - m); s += p[g]; }
    float inv = 1.f / s;
    float c0 = 0, c1 = 0, c2 = 0, c3 = 0;
    #pragma unroll
    for (int g = 0; g < 16; ++g) {
        float w = p[g] * inv;
        c0 = fmaf(w, d_C[g][0], c0);
        c1 = fmaf(w, d_C[g][1], c1);
        c2 = fmaf(w, d_C[g][2], c2);
        c3 = fmaf(w, d_C[g][3], c3);
    }
    float* o = coefA + (k * 60 + node * 4);
    o[0] = c0; o[1] = c1; o[2] = c2; o[3] = c3;
}

__device__ __forceinline__ f32x2 bc(float s) { return (f32x2){s, s}; }
__device__ __forceinline__ f32x2 gate2(const float* c, f32x2 a, f32x2 b) {
    return __builtin_elementwise_fma(b,
               __builtin_elementwise_fma(a, bc(c[3]), bc(c[2])),
               __builtin_elementwise_fma(a, bc(c[1]), bc(c[0])));
}

// blockIdx = tile*8 + bp (XCD-pinned: the 64 blocks of a batch-pair share one
// XCD's L2, holding that pair's 2.1 MB of x). 512 threads = 8 waves; wave w
// covers k in [8w, 8w+8). One window staging serves all 64 k.
// lane = pixel of the 4x16 tile; f32x2 = 2 batch images.
__global__ __launch_bounds__(512) void logic_conv_kernel(
    const float* __restrict__ x, const int* __restrict__ loffA,
    const float* __restrict__ coefA, float* __restrict__ out)
{
    __shared__ f32x2 xt[WPOS];

    int tid = threadIdx.x;
    int bp  = blockIdx.x & 7;          // batch-pair == XCD slot
    int t   = blockIdx.x >> 3;         // tile 0..63
    int r0  = (t >> 2) * TH;
    int c0  = (t & 3) * TCW;

    const float* xb0 = x + (size_t)(2 * bp) * (CIN * HW * HW);
    const float* xb1 = xb0 + (CIN * HW * HW);

    // Stage interleaved padded 32x8x20 windows for both images (10 pos/thread).
    #pragma unroll
    for (int i = 0; i < 10; ++i) {
        int e  = tid + i * 512;
        int c  = e / (WR * WC);
        int r  = e - c * (WR * WC);
        int rr = r / WC;
        int cc = r - rr * WC;
        int ih = r0 + rr - PADDING, iw = c0 + cc - PADDING;
        f32x2 v = {0.f, 0.f};
        if ((unsigned)ih < HW && (unsigned)iw < HW) {
            int go = (c * HW + ih) * HW + iw;
            v.x = xb0[go];
            v.y = xb1[go];
        }
        xt[e] = v;
    }
    __syncthreads();

    int lane = tid & 63, wave = tid >> 6;
    int tr = lane >> 4, tc = lane & 15;
    int pxb   = (tr * WC + tc) * 8;            // per-lane LDS byte offset
    int pxout = (r0 + tr) * HW + (c0 + tc);    // per-lane output element offset
    float* outB0 = out + ((size_t)(2 * bp) << 18);
    float* outB1 = outB0 + (1 << 18);
    const char* xtb = (const char*)xt;

    int k0 = __builtin_amdgcn_readfirstlane(wave << 3);

    #pragma unroll 2
    for (int i = 0; i < 8; ++i) {
        int k = k0 + i;
        const int*   L = loffA + (k << 4);
        const float* C = coefA + k * 60;

        f32x2 g[16];
        #pragma unroll
        for (int n = 0; n < 16; ++n)
            g[n] = *(const f32x2*)(xtb + (L[n] + pxb));

        f32x2 v[8];
        #pragma unroll
        for (int n = 0; n < 8; ++n)
            v[n] = gate2(C + 4 * n, g[n], g[8 + n]);
        f32x2 u[4];
        #pragma unroll
        for (int n = 0; n < 4; ++n)
            u[n] = gate2(C + 32 + 4 * n, v[2 * n], v[2 * n + 1]);
        f32x2 t0 = gate2(C + 48, u[0], u[1]);
        f32x2 t1 = gate2(C + 52, u[2], u[3]);
        f32x2 r  = gate2(C + 56, t0, t1);

        int ko = (k << 12) + pxout;
        __builtin_nontemporal_store(r.x, &outB0[ko]);
        __builtin_nontemporal_store(r.y, &outB1[ko]);
    }
}

extern "C" void kernel_launch(void* const* d_in, const int* in_sizes, int n_in,
                              void* d_out, int out_size, void* d_ws, size_t ws_size,
                              hipStream_t stream) {
    const float* x     = (const float*)d_in[0];
    const int*   idx_h = (const int*)d_in[1];
    const int*   idx_w = (const int*)d_in[2];
    const int*   idx_c = (const int*)d_in[3];
    const float* w0    = (const float*)d_in[4];
    const float* w1    = (const float*)d_in[5];
    const float* w2    = (const float*)d_in[6];
    const float* w3    = (const float*)d_in[7];
    float* out   = (float*)d_out;

    float* coefA = (float*)d_ws;                      // 15,360 B
    int*   loffA = (int*)((char*)d_ws + 16384);       // 4,096 B

    hipLaunchKernelGGL(prep_kernel, dim3(5), dim3(256), 0, stream,
                       idx_h, idx_w, idx_c, w0, w1, w2, w3, coefA, loffA);
    // 64 tiles * 8 batch-pairs = 512 blocks, 512 threads, XCD-pinned by bp
    hipLaunchKernelGGL(logic_conv_kernel, dim3(512), dim3(512), 0, stream,
                       x, loffA, coefA, out);
}